// Round 4
// baseline (9161.623 us; speedup 1.0000x reference)
//
#include <hip/hip_runtime.h>
#include <hip/hip_bf16.h>
#include <stdint.h>

// dMaSIFConv — paranoid correctness build.
// N=8192, I=16, H=O=64, CUTS=8, GROUPS=4.
// Wire dtype (bf16 vs fp32) detected per-kernel from gn_in_w (all-ones):
// dword0 == 0x3F800000 -> fp32, else (0x3F803F80) -> bf16. All compute fp32.
// No cross-lane ops, no conv LDS, no atomics, no inter-kernel stat passing
// beyond plain global writes. Design goal: eliminate entire bug classes.

#define N_PTS   8192
#define PSCALE  0.07856742013183861f   // 1/(sqrt(2)*9)
#define GN_CNT  (N_PTS * 16)           // per-group element count (N * 64/4)

// dtype-adaptive element load
__device__ __forceinline__ float ldx(const void* p, int i, bool bf) {
  return bf ? __bfloat162float(((const __hip_bfloat16*)p)[i])
            : ((const float*)p)[i];
}
__device__ __forceinline__ bool is_bf(const uint32_t* dref) {
  return dref[0] != 0x3F800000u;
}
__device__ __forceinline__ float leaky(float x) { return x > 0.f ? x : 0.2f * x; }

// ---------------- input MLP: fbuf = leaky(leaky(feat@W1^T+b1)@W2^T+b2) ------
__global__ __launch_bounds__(256) void mlp_in_kernel(
    const void* __restrict__ feat, const void* __restrict__ W1,
    const void* __restrict__ b1,   const void* __restrict__ W2,
    const void* __restrict__ b2,   float* __restrict__ fbuf,
    const uint32_t* __restrict__ dref) {
  const bool bf = is_bf(dref);
  __shared__ float ls[4][64];
  const int t = threadIdx.x, nl = t >> 6, h = t & 63;
  const int n = blockIdx.x * 4 + nl;
  float a = ldx(b1, h, bf);
#pragma unroll
  for (int i = 0; i < 16; ++i)
    a = fmaf(ldx(feat, n * 16 + i, bf), ldx(W1, h * 16 + i, bf), a);
  ls[nl][h] = leaky(a);
  __syncthreads();
  float c = ldx(b2, h, bf);
#pragma unroll 8
  for (int k = 0; k < 64; ++k)
    c = fmaf(ls[nl][k], ldx(W2, h * 64 + k, bf), c);
  fbuf[n * 64 + h] = leaky(c);
}

// ---------------- output MLP (fp32 cbuf input) ------------------------------
__global__ __launch_bounds__(256) void mlp_out_kernel(
    const float* __restrict__ cbuf, const void* __restrict__ W1,
    const void* __restrict__ b1, const void* __restrict__ W2,
    const void* __restrict__ b2, float* __restrict__ obuf,
    const uint32_t* __restrict__ dref) {
  const bool bf = is_bf(dref);
  __shared__ float ls[4][64];
  const int t = threadIdx.x, nl = t >> 6, h = t & 63;
  const int n = blockIdx.x * 4 + nl;
  float a = ldx(b1, h, bf);
#pragma unroll 8
  for (int k = 0; k < 64; ++k)
    a = fmaf(cbuf[n * 64 + k], ldx(W1, h * 64 + k, bf), a);
  ls[nl][h] = leaky(a);
  __syncthreads();
  float c = ldx(b2, h, bf);
#pragma unroll 8
  for (int k = 0; k < 64; ++k)
    c = fmaf(ls[nl][k], ldx(W2, h * 64 + k, bf), c);
  obuf[n * 64 + h] = leaky(c);
}

// ---------------- GN stats: single block, LDS tree, no shfl/atomics ---------
__global__ __launch_bounds__(1024) void gn_stats_kernel(
    const float* __restrict__ buf, float* __restrict__ gstats) {
  __shared__ float sg[8][1024];
  const int t = threadIdx.x;
  const int g = (t & 63) >> 4;           // stride 1024 == 0 mod 64 -> fixed h
  float s = 0.f, q = 0.f;
  for (int idx = t; idx < N_PTS * 64; idx += 1024) {
    const float v = buf[idx];
    s += v; q = fmaf(v, v, q);
  }
#pragma unroll
  for (int r = 0; r < 8; ++r)
    sg[r][t] = (r == g) ? s : ((r == g + 4) ? q : 0.f);
  __syncthreads();
  for (int off = 512; off > 0; off >>= 1) {
    if (t < off) {
#pragma unroll
      for (int r = 0; r < 8; ++r) sg[r][t] += sg[r][t + off];
    }
    __syncthreads();
  }
  if (t < 8) gstats[t] = sg[t][0];
}

// ---------------- GN apply (in-place fp32) ----------------------------------
__global__ __launch_bounds__(256) void gn_apply_kernel(
    float* __restrict__ buf, const float* __restrict__ gstats,
    const void* __restrict__ gw, const void* __restrict__ gb,
    const uint32_t* __restrict__ dref) {
  const bool bf = is_bf(dref);
  const int idx = blockIdx.x * 256 + threadIdx.x;
  const int h = idx & 63, g = h >> 4;
  const float m = gstats[g] * (1.f / GN_CNT);
  const float v = gstats[4 + g] * (1.f / GN_CNT) - m * m;
  const float rs = rsqrtf(fmaxf(v, 0.f) + 1e-5f);
  buf[idx] = fmaf((buf[idx] - m) * rs, ldx(gw, h, bf), ldx(gb, h, bf));
}

// ---------------- GN apply + final store (dtype-branched) -------------------
__global__ __launch_bounds__(256) void gn_apply_out_kernel(
    const float* __restrict__ buf, const float* __restrict__ gstats,
    const void* __restrict__ gw, const void* __restrict__ gb,
    void* __restrict__ out, const uint32_t* __restrict__ dref) {
  const bool bf = is_bf(dref);
  const int idx = blockIdx.x * 256 + threadIdx.x;
  const int h = idx & 63, g = h >> 4;
  const float m = gstats[g] * (1.f / GN_CNT);
  const float v = gstats[4 + g] * (1.f / GN_CNT) - m * m;
  const float rs = rsqrtf(fmaxf(v, 0.f) + 1e-5f);
  const float r = fmaf((buf[idx] - m) * rs, ldx(gw, h, bf), ldx(gb, h, bf));
  if (bf) ((__hip_bfloat16*)out)[idx] = __float2bfloat16(r);
  else    ((float*)out)[idx] = r;
}

// ---------------- O(N^2) conv: zero LDS, zero barriers, zero cross-lane -----
// 4 independent waves per block; wave -> query b, lane -> channel h.
// For each n: every lane redundantly computes w(b,n) and the 8 hidden units
// from wave-uniform loads (identical values in all lanes -> no exchange),
// then g = relu(h.A2[lane]+B2[lane]); acc += w * f[n,lane] * g.
__global__ __launch_bounds__(256) void conv_kernel(
    const void* __restrict__ points, const void* __restrict__ nuv,
    const float* __restrict__ fbuf,
    const void* __restrict__ A1, const void* __restrict__ B1,
    const void* __restrict__ A2, const void* __restrict__ B2,
    float* __restrict__ cbuf, const uint32_t* __restrict__ dref) {
  const bool bf = is_bf(dref);
  const int t = threadIdx.x, lane = t & 63;
  const int b = blockIdx.x * 4 + (t >> 6);

  const float pbx = ldx(points, b * 3 + 0, bf) * PSCALE;
  const float pby = ldx(points, b * 3 + 1, bf) * PSCALE;
  const float pbz = ldx(points, b * 3 + 2, bf) * PSCALE;
  float nb[9];
#pragma unroll
  for (int i = 0; i < 9; ++i) nb[i] = ldx(nuv, b * 9 + i, bf);

  float a1v[24], b1v[8];
#pragma unroll
  for (int i = 0; i < 24; ++i) a1v[i] = ldx(A1, i, bf);
#pragma unroll
  for (int i = 0; i < 8; ++i)  b1v[i] = ldx(B1, i, bf);

  float a2r[8];
#pragma unroll
  for (int i = 0; i < 8; ++i)  a2r[i] = ldx(A2, lane * 8 + i, bf);
  const float b2h = ldx(B2, lane, bf);

  float acc = 0.f;
  for (int n = 0; n < N_PTS; ++n) {
    const float px = ldx(points, n * 3 + 0, bf) * PSCALE;
    const float py = ldx(points, n * 3 + 1, bf) * PSCALE;
    const float pz = ldx(points, n * 3 + 2, bf) * PSCALE;
    const float nx = ldx(nuv, n * 9 + 0, bf);
    const float ny = ldx(nuv, n * 9 + 1, bf);
    const float nz = ldx(nuv, n * 9 + 2, bf);

    const float dx = px - pbx, dy = py - pby, dz = pz - pbz;
    const float X0 = fmaf(nb[0], dx, fmaf(nb[1], dy, nb[2] * dz));
    const float X1 = fmaf(nb[3], dx, fmaf(nb[4], dy, nb[5] * dz));
    const float X2 = fmaf(nb[6], dx, fmaf(nb[7], dy, nb[8] * dz));
    const float dn = fmaf(nb[0], nx, fmaf(nb[1], ny, nb[2] * nz));
    const float dd = fmaf(dx, dx, fmaf(dy, dy, dz * dz));
    const float tt = 2.f - dn;
    const float w = __expf(-dd * tt * tt);

    float g = b2h;
#pragma unroll
    for (int c = 0; c < 8; ++c) {
      const float hc = fmaxf(fmaf(X0, a1v[c * 3 + 0],
                            fmaf(X1, a1v[c * 3 + 1],
                            fmaf(X2, a1v[c * 3 + 2], b1v[c]))), 0.f);
      g = fmaf(hc, a2r[c], g);
    }
    g = fmaxf(g, 0.f);
    acc = fmaf(w * fbuf[n * 64 + lane], g, acc);
  }
  cbuf[b * 64 + lane] = acc;
}

extern "C" void kernel_launch(void* const* d_in, const int* in_sizes, int n_in,
                              void* d_out, int out_size, void* d_ws, size_t ws_size,
                              hipStream_t stream) {
  (void)in_sizes; (void)n_in; (void)out_size; (void)ws_size;
  const void* points  = d_in[0];
  const void* nuv     = d_in[1];
  const void* feat    = d_in[2];
  const void* W_in1   = d_in[3];
  const void* b_in1   = d_in[4];
  const void* W_in2   = d_in[5];
  const void* b_in2   = d_in[6];
  const void* gn_in_w = d_in[7];
  const void* gn_in_b = d_in[8];
  const void* A1      = d_in[9];
  const void* B1      = d_in[10];
  const void* A2      = d_in[11];
  const void* B2      = d_in[12];
  const void* W_out1  = d_in[13];
  const void* b_out1  = d_in[14];
  const void* W_out2  = d_in[15];
  const void* b_out2  = d_in[16];
  const void* gn_out_w= d_in[17];
  const void* gn_out_b= d_in[18];
  const uint32_t* dref = (const uint32_t*)d_in[7];   // gn_in_w, all-ones

  float* fbuf   = (float*)d_ws;            // N*64 fp32
  float* cbuf   = fbuf + N_PTS * 64;       // N*64 fp32
  float* gstats = cbuf + N_PTS * 64;       // 16 floats (in:0-7, out:8-15)

  mlp_in_kernel<<<N_PTS / 4, 256, 0, stream>>>(feat, W_in1, b_in1, W_in2, b_in2,
                                               fbuf, dref);
  gn_stats_kernel<<<1, 1024, 0, stream>>>(fbuf, gstats);
  gn_apply_kernel<<<N_PTS * 64 / 256, 256, 0, stream>>>(fbuf, gstats,
                                                        gn_in_w, gn_in_b, dref);
  conv_kernel<<<N_PTS / 4, 256, 0, stream>>>(points, nuv, fbuf, A1, B1, A2, B2,
                                             cbuf, dref);
  mlp_out_kernel<<<N_PTS / 4, 256, 0, stream>>>(cbuf, W_out1, b_out1, W_out2,
                                                b_out2, fbuf, dref);
  gn_stats_kernel<<<1, 1024, 0, stream>>>(fbuf, gstats + 8);
  gn_apply_out_kernel<<<N_PTS * 64 / 256, 256, 0, stream>>>(
      fbuf, gstats + 8, gn_out_w, gn_out_b, d_out, dref);
}

// Round 5
// 1796.286 us; speedup vs baseline: 5.1003x; 5.1003x over previous
//
#include <hip/hip_runtime.h>
#include <hip/hip_bf16.h>
#include <stdint.h>

// dMaSIFConv — R5: known-good R4 pipeline, conv rebuilt with LDS phasing.
// N=8192, I=16, H=O=64, CUTS=8, GROUPS=4. Wire dtype bf16 (detected from
// gn_in_w dword0; fp32 fallback kept). All compute fp32 except the 8->64
// matvec in conv phase 2 (f16 v_dot2, f32 accumulate).
// R1-R3 root cause (fixed here): f_s staging wrote only 1024/4096 floats.

#define N_PTS   8192
#define CHUNK   64
#define NCHUNK  (N_PTS / CHUNK)
#define PSCALE  0.07856742013183861f   // 1/(sqrt(2)*9)
#define GN_CNT  (N_PTS * 16)           // per-group element count (N * 64/4)

typedef _Float16 half2_t __attribute__((ext_vector_type(2)));

#if __has_builtin(__builtin_amdgcn_fdot2)
__device__ __forceinline__ float dot2(half2_t a, half2_t b, float c) {
  return __builtin_amdgcn_fdot2(a, b, c, false);
}
#else
__device__ __forceinline__ float dot2(half2_t a, half2_t b, float c) {
  return fmaf((float)a.x, (float)b.x, fmaf((float)a.y, (float)b.y, c));
}
#endif

// dtype-adaptive element load
__device__ __forceinline__ float ldx(const void* p, int i, bool bf) {
  return bf ? __bfloat162float(((const __hip_bfloat16*)p)[i])
            : ((const float*)p)[i];
}
__device__ __forceinline__ bool is_bf(const uint32_t* dref) {
  return dref[0] != 0x3F800000u;
}
__device__ __forceinline__ float leaky(float x) { return x > 0.f ? x : 0.2f * x; }

// ---------------- input MLP: fbuf = leaky(leaky(feat@W1^T+b1)@W2^T+b2) ------
__global__ __launch_bounds__(256) void mlp_in_kernel(
    const void* __restrict__ feat, const void* __restrict__ W1,
    const void* __restrict__ b1,   const void* __restrict__ W2,
    const void* __restrict__ b2,   float* __restrict__ fbuf,
    const uint32_t* __restrict__ dref) {
  const bool bf = is_bf(dref);
  __shared__ float ls[4][64];
  const int t = threadIdx.x, nl = t >> 6, h = t & 63;
  const int n = blockIdx.x * 4 + nl;
  float a = ldx(b1, h, bf);
#pragma unroll
  for (int i = 0; i < 16; ++i)
    a = fmaf(ldx(feat, n * 16 + i, bf), ldx(W1, h * 16 + i, bf), a);
  ls[nl][h] = leaky(a);
  __syncthreads();
  float c = ldx(b2, h, bf);
#pragma unroll 8
  for (int k = 0; k < 64; ++k)
    c = fmaf(ls[nl][k], ldx(W2, h * 64 + k, bf), c);
  fbuf[n * 64 + h] = leaky(c);
}

// ---------------- output MLP (fp32 cbuf input) ------------------------------
__global__ __launch_bounds__(256) void mlp_out_kernel(
    const float* __restrict__ cbuf, const void* __restrict__ W1,
    const void* __restrict__ b1, const void* __restrict__ W2,
    const void* __restrict__ b2, float* __restrict__ obuf,
    const uint32_t* __restrict__ dref) {
  const bool bf = is_bf(dref);
  __shared__ float ls[4][64];
  const int t = threadIdx.x, nl = t >> 6, h = t & 63;
  const int n = blockIdx.x * 4 + nl;
  float a = ldx(b1, h, bf);
#pragma unroll 8
  for (int k = 0; k < 64; ++k)
    a = fmaf(cbuf[n * 64 + k], ldx(W1, h * 64 + k, bf), a);
  ls[nl][h] = leaky(a);
  __syncthreads();
  float c = ldx(b2, h, bf);
#pragma unroll 8
  for (int k = 0; k < 64; ++k)
    c = fmaf(ls[nl][k], ldx(W2, h * 64 + k, bf), c);
  obuf[n * 64 + h] = leaky(c);
}

// ---------------- GN stats: single block, LDS tree, no shfl/atomics ---------
__global__ __launch_bounds__(1024) void gn_stats_kernel(
    const float* __restrict__ buf, float* __restrict__ gstats) {
  __shared__ float sg[8][1024];
  const int t = threadIdx.x;
  const int g = (t & 63) >> 4;           // stride 1024 == 0 mod 64 -> fixed h
  float s = 0.f, q = 0.f;
  for (int idx = t; idx < N_PTS * 64; idx += 1024) {
    const float v = buf[idx];
    s += v; q = fmaf(v, v, q);
  }
#pragma unroll
  for (int r = 0; r < 8; ++r)
    sg[r][t] = (r == g) ? s : ((r == g + 4) ? q : 0.f);
  __syncthreads();
  for (int off = 512; off > 0; off >>= 1) {
    if (t < off) {
#pragma unroll
      for (int r = 0; r < 8; ++r) sg[r][t] += sg[r][t + off];
    }
    __syncthreads();
  }
  if (t < 8) gstats[t] = sg[t][0];
}

// ---------------- GN apply (in-place fp32) ----------------------------------
__global__ __launch_bounds__(256) void gn_apply_kernel(
    float* __restrict__ buf, const float* __restrict__ gstats,
    const void* __restrict__ gw, const void* __restrict__ gb,
    const uint32_t* __restrict__ dref) {
  const bool bf = is_bf(dref);
  const int idx = blockIdx.x * 256 + threadIdx.x;
  const int h = idx & 63, g = h >> 4;
  const float m = gstats[g] * (1.f / GN_CNT);
  const float v = gstats[4 + g] * (1.f / GN_CNT) - m * m;
  const float rs = rsqrtf(fmaxf(v, 0.f) + 1e-5f);
  buf[idx] = fmaf((buf[idx] - m) * rs, ldx(gw, h, bf), ldx(gb, h, bf));
}

// ---------------- GN apply + final store (dtype-branched) -------------------
__global__ __launch_bounds__(256) void gn_apply_out_kernel(
    const float* __restrict__ buf, const float* __restrict__ gstats,
    const void* __restrict__ gw, const void* __restrict__ gb,
    void* __restrict__ out, const uint32_t* __restrict__ dref) {
  const bool bf = is_bf(dref);
  const int idx = blockIdx.x * 256 + threadIdx.x;
  const int h = idx & 63, g = h >> 4;
  const float m = gstats[g] * (1.f / GN_CNT);
  const float v = gstats[4 + g] * (1.f / GN_CNT) - m * m;
  const float rs = rsqrtf(fmaxf(v, 0.f) + 1e-5f);
  const float r = fmaf((buf[idx] - m) * rs, ldx(gw, h, bf), ldx(gb, h, bf));
  if (bf) ((__hip_bfloat16*)out)[idx] = __float2bfloat16(r);
  else    ((float*)out)[idx] = r;
}

// ---------------- O(N^2) conv: LDS-phased (R2 structure, staging FIXED) -----
// 1 wave per query b (lane = channel h); 4 waves/block share the LDS f-tile.
// Phase 1: lane j computes w_j and hc_j[0..7] for n = chunk*64+j, packs hc to
// 4x f16x2 -> one float4 LDS write (per-wave tile, no cross-wave dep).
// Phase 2 per j: w b32 broadcast + hc b128 broadcast + f b32 stride-1 (all
// conflict-free) + 4x v_dot2_f32_f16 + relu + fma.
__global__ __launch_bounds__(256) void conv_kernel(
    const void* __restrict__ points, const void* __restrict__ nuv,
    const float* __restrict__ fbuf,
    const void* __restrict__ A1, const void* __restrict__ B1,
    const void* __restrict__ A2, const void* __restrict__ B2,
    float* __restrict__ cbuf, const uint32_t* __restrict__ dref) {
  const bool bf = is_bf(dref);
  __shared__ float  f_s[CHUNK * 64];       // 16 KB = full 64n x 64h tile
  __shared__ float4 hcp_s[4][CHUNK];       // 4 KB packed f16 hidden units
  __shared__ float  w_s[4][CHUNK];         // 1 KB

  const int t = threadIdx.x;
  const int wv = t >> 6, lane = t & 63;
  const int b = blockIdx.x * 4 + wv;

  // per-wave uniform query data (lane-uniform values; correctness-safe)
  const float pbx = ldx(points, b * 3 + 0, bf) * PSCALE;
  const float pby = ldx(points, b * 3 + 1, bf) * PSCALE;
  const float pbz = ldx(points, b * 3 + 2, bf) * PSCALE;
  float nb[9];
#pragma unroll
  for (int i = 0; i < 9; ++i) nb[i] = ldx(nuv, b * 9 + i, bf);

  float a1v[24], b1v[8];
#pragma unroll
  for (int i = 0; i < 24; ++i) a1v[i] = ldx(A1, i, bf);
#pragma unroll
  for (int i = 0; i < 8; ++i)  b1v[i] = ldx(B1, i, bf);

  // per-lane A2 row (h = lane) as f16 pairs + B2
  half2_t a2h[4];
#pragma unroll
  for (int i = 0; i < 4; ++i) {
    a2h[i].x = (_Float16)ldx(A2, lane * 8 + 2 * i + 0, bf);
    a2h[i].y = (_Float16)ldx(A2, lane * 8 + 2 * i + 1, bf);
  }
  const float b2h = ldx(B2, lane, bf);

  float acc = 0.f;
  const float4* fg4 = (const float4*)fbuf;

  for (int c = 0; c < NCHUNK; ++c) {
    // prefetch the full 4096-float f chunk: FOUR float4 per thread (the fix)
    const float4 fv0 = fg4[c * 1024 + t];
    const float4 fv1 = fg4[c * 1024 + t + 256];
    const float4 fv2 = fg4[c * 1024 + t + 512];
    const float4 fv3 = fg4[c * 1024 + t + 768];
    // phase-1 inputs for this lane's n
    const int n = c * CHUNK + lane;
    const float px = ldx(points, n * 3 + 0, bf) * PSCALE;
    const float py = ldx(points, n * 3 + 1, bf) * PSCALE;
    const float pz = ldx(points, n * 3 + 2, bf) * PSCALE;
    const float nx = ldx(nuv, n * 9 + 0, bf);
    const float ny = ldx(nuv, n * 9 + 1, bf);
    const float nz = ldx(nuv, n * 9 + 2, bf);

    __syncthreads();                       // prior chunk's f_s reads done
    ((float4*)f_s)[t]       = fv0;
    ((float4*)f_s)[t + 256] = fv1;
    ((float4*)f_s)[t + 512] = fv2;
    ((float4*)f_s)[t + 768] = fv3;

    // phase 1: per-lane n
    const float dx = px - pbx, dy = py - pby, dz = pz - pbz;
    const float X0 = fmaf(nb[0], dx, fmaf(nb[1], dy, nb[2] * dz));
    const float X1 = fmaf(nb[3], dx, fmaf(nb[4], dy, nb[5] * dz));
    const float X2 = fmaf(nb[6], dx, fmaf(nb[7], dy, nb[8] * dz));
    const float dn = fmaf(nb[0], nx, fmaf(nb[1], ny, nb[2] * nz));
    const float dd = fmaf(dx, dx, fmaf(dy, dy, dz * dz));
    const float tt = 2.f - dn;
    w_s[wv][lane] = __expf(-dd * tt * tt);

    float hc[8];
#pragma unroll
    for (int cc = 0; cc < 8; ++cc)
      hc[cc] = fmaxf(fmaf(X0, a1v[cc * 3 + 0],
                     fmaf(X1, a1v[cc * 3 + 1],
                     fmaf(X2, a1v[cc * 3 + 2], b1v[cc]))), 0.f);
    half2_t p01; p01.x = (_Float16)hc[0]; p01.y = (_Float16)hc[1];
    half2_t p23; p23.x = (_Float16)hc[2]; p23.y = (_Float16)hc[3];
    half2_t p45; p45.x = (_Float16)hc[4]; p45.y = (_Float16)hc[5];
    half2_t p67; p67.x = (_Float16)hc[6]; p67.y = (_Float16)hc[7];
    float4 pk;
    pk.x = __builtin_bit_cast(float, p01);
    pk.y = __builtin_bit_cast(float, p23);
    pk.z = __builtin_bit_cast(float, p45);
    pk.w = __builtin_bit_cast(float, p67);
    hcp_s[wv][lane] = pk;

    __syncthreads();                       // f_s (cross-wave) + tiles visible

    // phase 2: accumulate over the 64 n's of this chunk
#pragma unroll 8
    for (int j = 0; j < CHUNK; ++j) {
      const float4 hp = hcp_s[wv][j];
      const float wj = w_s[wv][j];
      float g = b2h;
      g = dot2(__builtin_bit_cast(half2_t, hp.x), a2h[0], g);
      g = dot2(__builtin_bit_cast(half2_t, hp.y), a2h[1], g);
      g = dot2(__builtin_bit_cast(half2_t, hp.z), a2h[2], g);
      g = dot2(__builtin_bit_cast(half2_t, hp.w), a2h[3], g);
      g = fmaxf(g, 0.f);
      acc = fmaf(wj * f_s[j * 64 + lane], g, acc);
    }
  }
  cbuf[b * 64 + lane] = acc;
}

extern "C" void kernel_launch(void* const* d_in, const int* in_sizes, int n_in,
                              void* d_out, int out_size, void* d_ws, size_t ws_size,
                              hipStream_t stream) {
  (void)in_sizes; (void)n_in; (void)out_size; (void)ws_size;
  const void* points  = d_in[0];
  const void* nuv     = d_in[1];
  const void* feat    = d_in[2];
  const void* W_in1   = d_in[3];
  const void* b_in1   = d_in[4];
  const void* W_in2   = d_in[5];
  const void* b_in2   = d_in[6];
  const void* gn_in_w = d_in[7];
  const void* gn_in_b = d_in[8];
  const void* A1      = d_in[9];
  const void* B1      = d_in[10];
  const void* A2      = d_in[11];
  const void* B2      = d_in[12];
  const void* W_out1  = d_in[13];
  const void* b_out1  = d_in[14];
  const void* W_out2  = d_in[15];
  const void* b_out2  = d_in[16];
  const void* gn_out_w= d_in[17];
  const void* gn_out_b= d_in[18];
  const uint32_t* dref = (const uint32_t*)d_in[7];   // gn_in_w, all-ones

  float* fbuf   = (float*)d_ws;            // N*64 fp32
  float* cbuf   = fbuf + N_PTS * 64;       // N*64 fp32
  float* gstats = cbuf + N_PTS * 64;       // 16 floats (in:0-7, out:8-15)

  mlp_in_kernel<<<N_PTS / 4, 256, 0, stream>>>(feat, W_in1, b_in1, W_in2, b_in2,
                                               fbuf, dref);
  gn_stats_kernel<<<1, 1024, 0, stream>>>(fbuf, gstats);
  gn_apply_kernel<<<N_PTS * 64 / 256, 256, 0, stream>>>(fbuf, gstats,
                                                        gn_in_w, gn_in_b, dref);
  conv_kernel<<<N_PTS / 4, 256, 0, stream>>>(points, nuv, fbuf, A1, B1, A2, B2,
                                             cbuf, dref);
  mlp_out_kernel<<<N_PTS / 4, 256, 0, stream>>>(cbuf, W_out1, b_out1, W_out2,
                                                b_out2, fbuf, dref);
  gn_stats_kernel<<<1, 1024, 0, stream>>>(fbuf, gstats + 8);
  gn_apply_out_kernel<<<N_PTS * 64 / 256, 256, 0, stream>>>(
      fbuf, gstats + 8, gn_out_w, gn_out_b, d_out, dref);
}

// Round 6
// 1262.986 us; speedup vs baseline: 7.2539x; 1.4223x over previous
//
#include <hip/hip_runtime.h>
#include <hip/hip_bf16.h>
#include <stdint.h>

// dMaSIFConv — R6: convert-once fp32 pool, conv with 8-wave blocks (4/CU
// exact), fully-unrolled immediate-offset inner loop, SGPR-pinned uniforms.
// N=8192, I=16, H=O=64, CUTS=8, GROUPS=4. Wire dtype bf16 (detect kept).

#define N_PTS   8192
#define CHUNK   64
#define NCHUNK  (N_PTS / CHUNK)
#define WPB     8                       // waves per conv block
#define PSCALE  0.07856742013183861f    // 1/(sqrt(2)*9)
#define GN_CNT  (N_PTS * 16)

// fp32 pool offsets (prefix sums of input element counts)
#define OFF_POINTS 0
#define OFF_NUV    24576
#define OFF_FEAT   98304
#define OFF_WIN1   229376
#define OFF_BIN1   230400
#define OFF_WIN2   230464
#define OFF_BIN2   234560
#define OFF_GNIW   234624
#define OFF_GNIB   234688
#define OFF_A1     234752
#define OFF_B1     234776
#define OFF_A2     234784
#define OFF_B2     235296
#define OFF_WOUT1  235360
#define OFF_BOUT1  239456
#define OFF_WOUT2  239520
#define OFF_BOUT2  243616
#define OFF_GNOW   243680
#define OFF_GNOB   243744
#define CVT_TOTAL  243808
#define NSEG 19

typedef _Float16 half2_t __attribute__((ext_vector_type(2)));

#if __has_builtin(__builtin_amdgcn_fdot2)
__device__ __forceinline__ float dot2(half2_t a, half2_t b, float c) {
  return __builtin_amdgcn_fdot2(a, b, c, false);
}
#else
__device__ __forceinline__ float dot2(half2_t a, half2_t b, float c) {
  return fmaf((float)a.x, (float)b.x, fmaf((float)a.y, (float)b.y, c));
}
#endif

struct InPtrs { const void* p[NSEG]; };

__device__ __forceinline__ float rfl(float x) {
  return __int_as_float(__builtin_amdgcn_readfirstlane(__float_as_int(x)));
}
__device__ __forceinline__ float leaky(float x) { return x > 0.f ? x : 0.2f * x; }

// ---------------- prep: detect dtype, convert all inputs to fp32 pool -------
// Segment 0 (points) is pre-scaled by PSCALE. Also zeroes gstats[0..15].
__global__ __launch_bounds__(256) void prep_kernel(InPtrs ptrs, float* dst,
                                                   float* gstats) {
  if (blockIdx.x == 0 && threadIdx.x < 16) gstats[threadIdx.x] = 0.f;
  const uint32_t w0 = ((const uint32_t*)ptrs.p[7])[0];   // gn_in_w (all ones)
  const bool bf = (w0 != 0x3F800000u);
  const int CUM[NSEG + 1] = {0, 24576, 98304, 229376, 230400, 230464, 234560,
                             234624, 234688, 234752, 234776, 234784, 235296,
                             235360, 239456, 239520, 243616, 243680, 243744,
                             243808};
  for (int e = blockIdx.x * 256 + threadIdx.x; e < CVT_TOTAL;
       e += gridDim.x * 256) {
    int s = 0;
#pragma unroll
    for (int i = 1; i < NSEG; ++i) s += (e >= CUM[i]) ? 1 : 0;
    const int rem = e - CUM[s];
    float v = bf ? __bfloat162float(((const __hip_bfloat16*)ptrs.p[s])[rem])
                 : ((const float*)ptrs.p[s])[rem];
    if (s == 0) v *= PSCALE;
    dst[e] = v;
  }
}

// ---------------- input MLP (fp32 pool, float4 loads) -----------------------
__global__ __launch_bounds__(256) void mlp_in_kernel(
    const float* __restrict__ pool, float* __restrict__ fbuf) {
  __shared__ float ls[4][64];
  const int t = threadIdx.x, nl = t >> 6, h = t & 63;
  const int n = blockIdx.x * 4 + nl;
  const float4* fr = (const float4*)(pool + OFF_FEAT + n * 16);
  const float4* w1 = (const float4*)(pool + OFF_WIN1 + h * 16);
  float a = pool[OFF_BIN1 + h];
#pragma unroll
  for (int k = 0; k < 4; ++k) {
    const float4 x = fr[k], w = w1[k];
    a = fmaf(x.x, w.x, a); a = fmaf(x.y, w.y, a);
    a = fmaf(x.z, w.z, a); a = fmaf(x.w, w.w, a);
  }
  ls[nl][h] = leaky(a);
  __syncthreads();
  const float4* w2 = (const float4*)(pool + OFF_WIN2 + h * 64);
  const float4* lr = (const float4*)&ls[nl][0];
  float c = pool[OFF_BIN2 + h];
#pragma unroll
  for (int k = 0; k < 16; ++k) {
    const float4 x = lr[k], w = w2[k];
    c = fmaf(x.x, w.x, c); c = fmaf(x.y, w.y, c);
    c = fmaf(x.z, w.z, c); c = fmaf(x.w, w.w, c);
  }
  fbuf[n * 64 + h] = leaky(c);
}

// ---------------- output MLP (fp32 cbuf input) ------------------------------
__global__ __launch_bounds__(256) void mlp_out_kernel(
    const float* __restrict__ cbuf, const float* __restrict__ pool,
    float* __restrict__ obuf) {
  __shared__ float ls[4][64];
  const int t = threadIdx.x, nl = t >> 6, h = t & 63;
  const int n = blockIdx.x * 4 + nl;
  const float4* cr = (const float4*)(cbuf + n * 64);
  const float4* w1 = (const float4*)(pool + OFF_WOUT1 + h * 64);
  float a = pool[OFF_BOUT1 + h];
#pragma unroll
  for (int k = 0; k < 16; ++k) {
    const float4 x = cr[k], w = w1[k];
    a = fmaf(x.x, w.x, a); a = fmaf(x.y, w.y, a);
    a = fmaf(x.z, w.z, a); a = fmaf(x.w, w.w, a);
  }
  ls[nl][h] = leaky(a);
  __syncthreads();
  const float4* w2 = (const float4*)(pool + OFF_WOUT2 + h * 64);
  const float4* lr = (const float4*)&ls[nl][0];
  float c = pool[OFF_BOUT2 + h];
#pragma unroll
  for (int k = 0; k < 16; ++k) {
    const float4 x = lr[k], w = w2[k];
    c = fmaf(x.x, w.x, c); c = fmaf(x.y, w.y, c);
    c = fmaf(x.z, w.z, c); c = fmaf(x.w, w.w, c);
  }
  obuf[n * 64 + h] = leaky(c);
}

// ---------------- GN stats: 64 blocks, LDS + global atomics -----------------
__global__ __launch_bounds__(256) void gn_stats_kernel(
    const float* __restrict__ buf, float* __restrict__ gstats) {
  __shared__ float red[8];
  const int t = threadIdx.x;
  const int g = (t & 63) >> 4;           // stride 256 == 0 mod 64 -> fixed h
  if (t < 8) red[t] = 0.f;
  float s = 0.f, q = 0.f;
  for (int idx = blockIdx.x * 256 + t; idx < N_PTS * 64; idx += 64 * 256) {
    const float v = buf[idx];
    s += v; q = fmaf(v, v, q);
  }
  __syncthreads();
  atomicAdd(&red[g], s);
  atomicAdd(&red[4 + g], q);
  __syncthreads();
  if (t < 8) atomicAdd(&gstats[t], red[t]);
}

// ---------------- GN apply (in-place fp32) ----------------------------------
__global__ __launch_bounds__(256) void gn_apply_kernel(
    float* __restrict__ buf, const float* __restrict__ gstats,
    const float* __restrict__ pool) {
  const int idx = blockIdx.x * 256 + threadIdx.x;
  const int h = idx & 63, g = h >> 4;
  const float m = gstats[g] * (1.f / GN_CNT);
  const float v = gstats[4 + g] * (1.f / GN_CNT) - m * m;
  const float rs = rsqrtf(fmaxf(v, 0.f) + 1e-5f);
  buf[idx] = fmaf((buf[idx] - m) * rs, pool[OFF_GNIW + h], pool[OFF_GNIB + h]);
}

// ---------------- GN apply + final store (dtype-branched) -------------------
__global__ __launch_bounds__(256) void gn_apply_out_kernel(
    const float* __restrict__ buf, const float* __restrict__ gstats,
    const float* __restrict__ pool, void* __restrict__ out,
    const uint32_t* __restrict__ dref) {
  const bool bf = (dref[0] != 0x3F800000u);
  const int idx = blockIdx.x * 256 + threadIdx.x;
  const int h = idx & 63, g = h >> 4;
  const float m = gstats[g] * (1.f / GN_CNT);
  const float v = gstats[4 + g] * (1.f / GN_CNT) - m * m;
  const float rs = rsqrtf(fmaxf(v, 0.f) + 1e-5f);
  const float r = fmaf((buf[idx] - m) * rs, pool[OFF_GNOW + h], pool[OFF_GNOB + h]);
  if (bf) ((__hip_bfloat16*)out)[idx] = __float2bfloat16(r);
  else    ((float*)out)[idx] = r;
}

// ---------------- O(N^2) conv -----------------------------------------------
// 8 waves/block share the f-tile; 1024 blocks = exactly 4 blocks/CU.
// Phase 1: lane j computes w_j, hc_j[0..7] (f16-packed) for n = c*64+j.
// Phase 2: fully unrolled 64-j loop, immediate LDS offsets; per 4 j one
// ds_read_b128 of w; per j: hc b128 broadcast + f b32 + 4 dot2 + relu + fma.
__global__ __launch_bounds__(512, 8) void conv_kernel(
    const float* __restrict__ pool, const float* __restrict__ fbuf,
    float* __restrict__ cbuf) {
  __shared__ float  f_s[CHUNK * 64];       // 16 KB
  __shared__ float4 hcp_s[WPB][CHUNK];     // 8 KB
  __shared__ float4 w4_s[WPB][CHUNK / 4];  // 2 KB

  const float* pts32 = pool + OFF_POINTS;  // pre-scaled by PSCALE
  const float* nuv32 = pool + OFF_NUV;

  const int t = threadIdx.x;
  const int wv = t >> 6, lane = t & 63;
  const int b = blockIdx.x * WPB + wv;

  // wave-uniform query data pinned to SGPRs
  const float pbx = rfl(pts32[b * 3 + 0]);
  const float pby = rfl(pts32[b * 3 + 1]);
  const float pbz = rfl(pts32[b * 3 + 2]);
  float nb[9];
#pragma unroll
  for (int i = 0; i < 9; ++i) nb[i] = rfl(nuv32[b * 9 + i]);
  float a1v[24], b1v[8];
#pragma unroll
  for (int i = 0; i < 24; ++i) a1v[i] = rfl(pool[OFF_A1 + i]);
#pragma unroll
  for (int i = 0; i < 8; ++i)  b1v[i] = rfl(pool[OFF_B1 + i]);

  // per-lane A2 row (h = lane) as f16 pairs + B2
  half2_t a2h[4];
#pragma unroll
  for (int i = 0; i < 4; ++i) {
    a2h[i].x = (_Float16)pool[OFF_A2 + lane * 8 + 2 * i + 0];
    a2h[i].y = (_Float16)pool[OFF_A2 + lane * 8 + 2 * i + 1];
  }
  const float b2h = pool[OFF_B2 + lane];

  float acc = 0.f;
  const float4* fg4 = (const float4*)fbuf;

  for (int c = 0; c < NCHUNK; ++c) {
    // stage the 4096-float f chunk: 512 threads x 2 float4
    const float4 fv0 = fg4[c * 1024 + t];
    const float4 fv1 = fg4[c * 1024 + t + 512];
    // phase-1 inputs for this lane's n (pure fp32, pre-scaled)
    const int n = c * CHUNK + lane;
    const float px = pts32[n * 3 + 0];
    const float py = pts32[n * 3 + 1];
    const float pz = pts32[n * 3 + 2];
    const float nx = nuv32[n * 9 + 0];
    const float ny = nuv32[n * 9 + 1];
    const float nz = nuv32[n * 9 + 2];

    __syncthreads();                       // prior chunk's LDS reads done
    ((float4*)f_s)[t]       = fv0;
    ((float4*)f_s)[t + 512] = fv1;

    // phase 1
    const float dx = px - pbx, dy = py - pby, dz = pz - pbz;
    const float X0 = fmaf(nb[0], dx, fmaf(nb[1], dy, nb[2] * dz));
    const float X1 = fmaf(nb[3], dx, fmaf(nb[4], dy, nb[5] * dz));
    const float X2 = fmaf(nb[6], dx, fmaf(nb[7], dy, nb[8] * dz));
    const float dn = fmaf(nb[0], nx, fmaf(nb[1], ny, nb[2] * nz));
    const float dd = fmaf(dx, dx, fmaf(dy, dy, dz * dz));
    const float tt = 2.f - dn;
    ((float*)&w4_s[wv][0])[lane] = __expf(-dd * tt * tt);

    float hc[8];
#pragma unroll
    for (int cc = 0; cc < 8; ++cc)
      hc[cc] = fmaxf(fmaf(X0, a1v[cc * 3 + 0],
                     fmaf(X1, a1v[cc * 3 + 1],
                     fmaf(X2, a1v[cc * 3 + 2], b1v[cc]))), 0.f);
    half2_t p01; p01.x = (_Float16)hc[0]; p01.y = (_Float16)hc[1];
    half2_t p23; p23.x = (_Float16)hc[2]; p23.y = (_Float16)hc[3];
    half2_t p45; p45.x = (_Float16)hc[4]; p45.y = (_Float16)hc[5];
    half2_t p67; p67.x = (_Float16)hc[6]; p67.y = (_Float16)hc[7];
    float4 pk;
    pk.x = __builtin_bit_cast(float, p01);
    pk.y = __builtin_bit_cast(float, p23);
    pk.z = __builtin_bit_cast(float, p45);
    pk.w = __builtin_bit_cast(float, p67);
    hcp_s[wv][lane] = pk;

    __syncthreads();                       // all tiles visible

    // phase 2: fully unrolled, immediate offsets
#pragma unroll
    for (int jg = 0; jg < CHUNK / 4; ++jg) {
      const float4 w4 = w4_s[wv][jg];
#pragma unroll
      for (int k = 0; k < 4; ++k) {
        const int j = jg * 4 + k;
        const float fj = f_s[j * 64 + lane];
        const float4 hp = hcp_s[wv][j];
        const float wj = (k == 0) ? w4.x : (k == 1) ? w4.y : (k == 2) ? w4.z : w4.w;
        float g = b2h;
        g = dot2(__builtin_bit_cast(half2_t, hp.x), a2h[0], g);
        g = dot2(__builtin_bit_cast(half2_t, hp.y), a2h[1], g);
        g = dot2(__builtin_bit_cast(half2_t, hp.z), a2h[2], g);
        g = dot2(__builtin_bit_cast(half2_t, hp.w), a2h[3], g);
        g = fmaxf(g, 0.f);
        acc = fmaf(wj * fj, g, acc);
      }
    }
  }
  cbuf[b * 64 + lane] = acc;
}

extern "C" void kernel_launch(void* const* d_in, const int* in_sizes, int n_in,
                              void* d_out, int out_size, void* d_ws, size_t ws_size,
                              hipStream_t stream) {
  (void)in_sizes; (void)n_in; (void)out_size; (void)ws_size;
  const uint32_t* dref = (const uint32_t*)d_in[7];   // gn_in_w, all-ones

  float* pool   = (float*)d_ws;               // CVT_TOTAL fp32 inputs
  float* fbuf   = pool + CVT_TOTAL;           // N*64
  float* cbuf   = fbuf + N_PTS * 64;          // N*64
  float* gstats = cbuf + N_PTS * 64;          // 16 (in:0-7, out:8-15)

  InPtrs ptrs;
  for (int i = 0; i < NSEG; ++i) ptrs.p[i] = d_in[i];

  prep_kernel<<<256, 256, 0, stream>>>(ptrs, pool, gstats);
  mlp_in_kernel<<<N_PTS / 4, 256, 0, stream>>>(pool, fbuf);
  gn_stats_kernel<<<64, 256, 0, stream>>>(fbuf, gstats);
  gn_apply_kernel<<<N_PTS * 64 / 256, 256, 0, stream>>>(fbuf, gstats, pool);
  conv_kernel<<<N_PTS / WPB, 512, 0, stream>>>(pool, fbuf, cbuf);
  mlp_out_kernel<<<N_PTS / 4, 256, 0, stream>>>(cbuf, pool, fbuf);
  gn_stats_kernel<<<64, 256, 0, stream>>>(fbuf, gstats + 8);
  gn_apply_out_kernel<<<N_PTS * 64 / 256, 256, 0, stream>>>(
      fbuf, gstats + 8, pool, d_out, dref);
}